// Round 1
// baseline (95.399 us; speedup 1.0000x reference)
//
#include <hip/hip_runtime.h>
#include <math.h>

#define N_WIRES 13
#define DIM 8192
#define N_LAYERS 3
#define N_OUT 10
#define BATCH 512
#define NTHREADS 512
#define ELEMS (DIM / NTHREADS)      // 16
#define PAIRS (DIM / 2 / NTHREADS)  // 8

__global__ __launch_bounds__(NTHREADS, 4) void vqc_kernel(
    const float* __restrict__ inputs,
    const float* __restrict__ weights,
    const float* __restrict__ embed,
    float* __restrict__ out)
{
    __shared__ float sr[DIM];
    __shared__ float si[DIM];
    __shared__ float coeff_s[N_WIRES];
    __shared__ float gamma_s[N_WIRES];
    __shared__ float uu[N_WIRES][8];  // u00r,u00i,u01r,u01i,u10r,u10i,u11r,u11i
    __shared__ float red[(NTHREADS / 64) * N_OUT];

    const int b   = blockIdx.x;
    const int tid = threadIdx.x;

    for (int l = 0; l < N_LAYERS; ++l) {
        // ---- per-layer parameters (13 threads) ----
        if (tid < N_WIRES) {
            const int base = (l * N_WIRES + tid) * 3;
            const float om = embed[base + 0];
            const float bi = embed[base + 1];
            const float ga = embed[base + 2];
            coeff_s[tid] = inputs[b * N_WIRES + tid] * om + bi;
            gamma_s[tid] = ga;

            const float phi = weights[base + 0];
            const float th  = weights[base + 1];
            const float omg = weights[base + 2];
            float c, s, ca, sa, cb, sb;
            __sincosf(0.5f * th, &s, &c);
            __sincosf(0.5f * (phi + omg), &sa, &ca);
            __sincosf(0.5f * (phi - omg), &sb, &cb);
            // U00 = ep*c ; ep = cos(a) - i sin(a)
            uu[tid][0] =  ca * c;  uu[tid][1] = -sa * c;
            // U01 = -conj(em)*s ; conj(em) = cos(b2) + i sin(b2)
            uu[tid][2] = -cb * s;  uu[tid][3] = -sb * s;
            // U10 = em*s
            uu[tid][4] =  cb * s;  uu[tid][5] = -sb * s;
            // U11 = conj(ep)*c
            uu[tid][6] =  ca * c;  uu[tid][7] =  sa * c;
        }
        __syncthreads();

        // ---- diagonal phase: psi *= exp(-i * ang(x)) ----
        float S = 0.f;
        #pragma unroll
        for (int w = 0; w < N_WIRES; ++w) S += coeff_s[w] + gamma_s[w];

        #pragma unroll
        for (int k = 0; k < ELEMS; ++k) {
            const int x = tid + k * NTHREADS;
            // e_j = x_j XOR x_{(j-1) mod 13}  (ZZ parity word)
            const int e = x ^ (((x << 1) | (x >> (N_WIRES - 1))) & (DIM - 1));
            float ang = S;
            #pragma unroll
            for (int w = 0; w < N_WIRES; ++w) {
                const int j = N_WIRES - 1 - w;
                if ((x >> j) & 1) ang -= 2.f * coeff_s[w];
                if ((e >> j) & 1) ang -= 2.f * gamma_s[w];
            }
            float sn, cs;
            __sincosf(ang, &sn, &cs);
            if (l == 0) {
                const float nrm = 0.011048543456039806f;  // 8192^-0.5
                sr[x] =  nrm * cs;
                si[x] = -nrm * sn;
            } else {
                const float r  = sr[x];
                const float ii = si[x];
                sr[x] = r * cs + ii * sn;
                si[x] = ii * cs - r * sn;
            }
        }
        __syncthreads();

        // ---- 13 single-qubit Rot gates (one LDS pass per wire) ----
        #pragma unroll 1
        for (int w = 0; w < N_WIRES; ++w) {
            const int bp = N_WIRES - 1 - w;
            const float u00r = uu[w][0], u00i = uu[w][1];
            const float u01r = uu[w][2], u01i = uu[w][3];
            const float u10r = uu[w][4], u10i = uu[w][5];
            const float u11r = uu[w][6], u11i = uu[w][7];
            #pragma unroll
            for (int k = 0; k < PAIRS; ++k) {
                const int p  = tid + k * NTHREADS;
                const int x0 = ((p >> bp) << (bp + 1)) | (p & ((1 << bp) - 1));
                const int x1 = x0 | (1 << bp);
                const float a0r = sr[x0], a0i = si[x0];
                const float a1r = sr[x1], a1i = si[x1];
                sr[x0] = u00r * a0r - u00i * a0i + u01r * a1r - u01i * a1i;
                si[x0] = u00r * a0i + u00i * a0r + u01r * a1i + u01i * a1r;
                sr[x1] = u10r * a0r - u10i * a0i + u11r * a1r - u11i * a1i;
                si[x1] = u10r * a0i + u10i * a0r + u11r * a1i + u11i * a1r;
            }
            __syncthreads();
        }

        // ---- ring of 13 CNOTs, composed into ONE basis permutation ----
        // psi_13[y] = psi_0[f_0(f_1(...f_12(y)))], f_i: flip bit(t_i) if bit(c_i)
        float tr[ELEMS], ti[ELEMS];
        #pragma unroll
        for (int k = 0; k < ELEMS; ++k) {
            const int y = tid + k * NTHREADS;
            int s = y;
            #pragma unroll
            for (int i = N_WIRES - 1; i >= 0; --i) {
                const int pc = N_WIRES - 1 - i;
                const int pt = N_WIRES - 1 - ((i + 1) % N_WIRES);
                s ^= ((s >> pc) & 1) << pt;
            }
            tr[k] = sr[s];
            ti[k] = si[s];
        }
        __syncthreads();
        #pragma unroll
        for (int k = 0; k < ELEMS; ++k) {
            const int y = tid + k * NTHREADS;
            sr[y] = tr[k];
            si[y] = ti[k];
        }
        __syncthreads();
    }

    // ---- readout: out[b][o] = sum_x |psi[x]|^2 * (1 - 2*bit_o(x)) ----
    float acc[N_OUT];
    #pragma unroll
    for (int o = 0; o < N_OUT; ++o) acc[o] = 0.f;

    #pragma unroll
    for (int k = 0; k < ELEMS; ++k) {
        const int x = tid + k * NTHREADS;
        const float p = sr[x] * sr[x] + si[x] * si[x];
        #pragma unroll
        for (int o = 0; o < N_OUT; ++o) {
            acc[o] += ((x >> (N_WIRES - 1 - o)) & 1) ? -p : p;
        }
    }

    // wave (64-lane) reduction, then cross-wave via LDS
    #pragma unroll
    for (int off = 32; off >= 1; off >>= 1) {
        #pragma unroll
        for (int o = 0; o < N_OUT; ++o) acc[o] += __shfl_down(acc[o], off);
    }
    const int wave = tid >> 6;
    const int lane = tid & 63;
    if (lane == 0) {
        #pragma unroll
        for (int o = 0; o < N_OUT; ++o) red[wave * N_OUT + o] = acc[o];
    }
    __syncthreads();
    if (tid < N_OUT) {
        float s = 0.f;
        #pragma unroll
        for (int w = 0; w < NTHREADS / 64; ++w) s += red[w * N_OUT + tid];
        out[b * N_OUT + tid] = s;
    }
}

extern "C" void kernel_launch(void* const* d_in, const int* in_sizes, int n_in,
                              void* d_out, int out_size, void* d_ws, size_t ws_size,
                              hipStream_t stream) {
    const float* inputs  = (const float*)d_in[0];
    const float* weights = (const float*)d_in[1];
    const float* embed   = (const float*)d_in[2];
    float* out = (float*)d_out;
    vqc_kernel<<<BATCH, NTHREADS, 0, stream>>>(inputs, weights, embed, out);
}

// Round 2
// 74.501 us; speedup vs baseline: 1.2805x; 1.2805x over previous
//
#include <hip/hip_runtime.h>
#include <math.h>

#define N_WIRES 13
#define DIM 8192
#define N_LAYERS 3
#define N_OUT 10
#define BATCH 512
#define NTHREADS 512

// Gate on a register bit: pairs (k0, k0|MASK) within the 16 per-thread amps.
#define REG_GATE(MASK, W) do { \
    const float u0r=uu[l][W][0], u0i=uu[l][W][1], u1r=uu[l][W][2], u1i=uu[l][W][3]; \
    const float u2r=uu[l][W][4], u2i=uu[l][W][5], u3r=uu[l][W][6], u3i=uu[l][W][7]; \
    _Pragma("unroll") \
    for (int k0 = 0; k0 < 16; ++k0) { \
        if (k0 & (MASK)) continue; \
        const int k1 = k0 | (MASK); \
        const float a0r=ar[k0], a0i=ai[k0], a1r=ar[k1], a1i=ai[k1]; \
        ar[k0] = u0r*a0r - u0i*a0i + u1r*a1r - u1i*a1i; \
        ai[k0] = u0r*a0i + u0i*a0r + u1r*a1i + u1i*a1r; \
        ar[k1] = u2r*a0r - u2i*a0i + u3r*a1r - u3i*a1i; \
        ai[k1] = u2r*a0i + u2i*a0r + u3r*a1i + u3i*a1r; \
    } \
} while (0)

// Gate on a lane bit: partner amplitudes via shfl_xor; lane computes its own row.
#define SHFL_GATE(MASK, W, BITP) do { \
    const float v0r=uu[l][W][0], v0i=uu[l][W][1], v1r=uu[l][W][2], v1i=uu[l][W][3]; \
    const float v2r=uu[l][W][4], v2i=uu[l][W][5], v3r=uu[l][W][6], v3i=uu[l][W][7]; \
    const bool hb = (tid >> (BITP)) & 1; \
    const float uar = hb ? v3r : v0r, uai = hb ? v3i : v0i; \
    const float upr = hb ? v2r : v1r, upi = hb ? v2i : v1i; \
    _Pragma("unroll") \
    for (int k = 0; k < 16; ++k) { \
        const float prr = __shfl_xor(ar[k], (MASK)); \
        const float pii = __shfl_xor(ai[k], (MASK)); \
        const float nr = uar*ar[k] - uai*ai[k] + upr*prr - upi*pii; \
        const float ni = uar*ai[k] + uai*ar[k] + upr*pii + upi*prr; \
        ar[k] = nr; ai[k] = ni; \
    } \
} while (0)

__device__ __forceinline__ void cmul(float& cr, float& ci,
                                     float xr, float xi, float yr, float yi) {
    cr = xr*yr - xi*yi;
    ci = xr*yi + xi*yr;
}

__global__ __launch_bounds__(NTHREADS, 4) void vqc_kernel(
    const float* __restrict__ inputs,
    const float* __restrict__ weights,
    const float* __restrict__ embed,
    float* __restrict__ out)
{
    __shared__ float sr[DIM];
    __shared__ float si[DIM];
    __shared__ float uu[N_LAYERS][N_WIRES][8];
    __shared__ float co[N_LAYERS][N_WIRES];
    __shared__ float ga[N_LAYERS][N_WIRES];
    __shared__ float eB[N_LAYERS][16][2];
    __shared__ float G3t[N_LAYERS][2];
    __shared__ float G12t[N_LAYERS][2];
    __shared__ float red[NTHREADS / 64][N_OUT];

    const int b   = blockIdx.x;
    const int tid = threadIdx.x;

    // ---- setup stage 1: per-(layer,wire) params + U matrices ----
    if (tid < N_LAYERS * N_WIRES) {
        const int l = tid / N_WIRES;
        const int w = tid - l * N_WIRES;
        const int base = (l * N_WIRES + w) * 3;
        const float om = embed[base + 0];
        const float bi = embed[base + 1];
        const float gm = embed[base + 2];
        co[l][w] = inputs[b * N_WIRES + w] * om + bi;
        ga[l][w] = gm;

        const float phi = weights[base + 0];
        const float th  = weights[base + 1];
        const float omg = weights[base + 2];
        float c, s, ca, sa, cb, sb;
        __sincosf(0.5f * th, &s, &c);
        __sincosf(0.5f * (phi + omg), &sa, &ca);
        __sincosf(0.5f * (phi - omg), &sb, &cb);
        uu[l][w][0] =  ca * c;  uu[l][w][1] = -sa * c;   // U00
        uu[l][w][2] = -cb * s;  uu[l][w][3] = -sb * s;   // U01
        uu[l][w][4] =  cb * s;  uu[l][w][5] = -sb * s;   // U10
        uu[l][w][6] =  ca * c;  uu[l][w][7] =  sa * c;   // U11

        if (w == 3)  { float s2, c2; __sincosf(2.f * gm, &s2, &c2); G3t[l][0]  = c2; G3t[l][1]  = s2; }
        if (w == 12) { float s2, c2; __sincosf(2.f * gm, &s2, &c2); G12t[l][0] = c2; G12t[l][1] = s2; }
    }
    __syncthreads();

    // ---- setup stage 2: k-part phase table (bits 9..12 of x = k) ----
    if (tid < N_LAYERS * 16) {
        const int l = tid >> 4;
        const int k = tid & 15;
        float B = 0.f;
        if (k & 8) B -= 2.f * co[l][0];           // x12 -> wire 0
        if (k & 4) B -= 2.f * co[l][1];
        if (k & 2) B -= 2.f * co[l][2];
        if (k & 1) B -= 2.f * co[l][3];
        if (((k >> 3) ^ (k >> 2)) & 1) B -= 2.f * ga[l][0];   // e12
        if (((k >> 2) ^ (k >> 1)) & 1) B -= 2.f * ga[l][1];   // e11
        if (((k >> 1) ^  k      ) & 1) B -= 2.f * ga[l][2];   // e10
        float sB, cB; __sincosf(B, &sB, &cB);
        eB[l][k][0] = cB; eB[l][k][1] = -sB;      // exp(-iB)
    }
    __syncthreads();

    float ar[16], ai[16];

    #pragma unroll 1
    for (int l = 0; l < N_LAYERS; ++l) {
        // ===== Pass A: x = tid | (k<<9); phase + wires 0-3 (reg) + 7-12 (shfl) =====
        // per-thread phase A(tid) = S - 2*(tid-local coeff/gamma terms)
        float S = 0.f;
        #pragma unroll
        for (int w = 0; w < N_WIRES; ++w) S += co[l][w] + ga[l][w];
        float A = S;
        #pragma unroll
        for (int w = 4; w <= 12; ++w)
            if ((tid >> (12 - w)) & 1) A -= 2.f * co[l][w];
        #pragma unroll
        for (int w = 4; w <= 11; ++w)
            if (((tid >> (12 - w)) ^ (tid >> (11 - w))) & 1) A -= 2.f * ga[l][w];

        float sA, cA; __sincosf(A, &sA, &cA);
        const float e0r = cA, e0i = -sA;          // exp(-iA)
        const float g3r = G3t[l][0],  g3i = G3t[l][1];    // exp(+2i*gamma3)
        const float gcr = G12t[l][0], gci = G12t[l][1];   // exp(+2i*gamma12)
        float e1r, e1i, e2r, e2i, e3r, e3i;
        cmul(e1r, e1i, e0r, e0i, g3r, g3i);
        cmul(e2r, e2i, e0r, e0i, gcr, gci);
        cmul(e3r, e3i, e1r, e1i, gcr, gci);
        const bool t8 = (tid >> 8) & 1;
        const bool t0 = (tid & 1) != 0;

        if (l == 0) {
            const float nrm = 0.011048543456039806f;   // 8192^-0.5
            #pragma unroll
            for (int k = 0; k < 16; ++k) {
                const bool c1 = ((k & 1) != 0) != t8;  // e9 = x9^x8
                const bool c2 = ((k & 8) != 0) != t0;  // e0 = x0^x12
                const float Er = c1 ? (c2 ? e3r : e1r) : (c2 ? e2r : e0r);
                const float Ei = c1 ? (c2 ? e3i : e1i) : (c2 ? e2i : e0i);
                float fr, fi;
                cmul(fr, fi, Er, Ei, eB[l][k][0], eB[l][k][1]);
                ar[k] = nrm * fr; ai[k] = nrm * fi;
            }
        } else {
            #pragma unroll
            for (int k = 0; k < 16; ++k) {
                const bool c1 = ((k & 1) != 0) != t8;
                const bool c2 = ((k & 8) != 0) != t0;
                const float Er = c1 ? (c2 ? e3r : e1r) : (c2 ? e2r : e0r);
                const float Ei = c1 ? (c2 ? e3i : e1i) : (c2 ? e2i : e0i);
                float fr, fi;
                cmul(fr, fi, Er, Ei, eB[l][k][0], eB[l][k][1]);
                const int x = tid + (k << 9);
                const float vr = sr[x], vi = si[x];
                ar[k] = vr * fr - vi * fi;
                ai[k] = vr * fi + vi * fr;
            }
        }

        REG_GATE(8, 0);   // wire 0 <-> x bit 12 <-> k bit 3
        REG_GATE(4, 1);
        REG_GATE(2, 2);
        REG_GATE(1, 3);
        SHFL_GATE(32, 7, 5);   // wire 7 <-> x bit 5 (lane bit 5)
        SHFL_GATE(16, 8, 4);
        SHFL_GATE(8,  9, 3);
        SHFL_GATE(4, 10, 2);
        SHFL_GATE(2, 11, 1);
        SHFL_GATE(1, 12, 0);

        #pragma unroll
        for (int k = 0; k < 16; ++k) {
            sr[tid + (k << 9)] = ar[k];
            si[tid + (k << 9)] = ai[k];
        }
        __syncthreads();

        // ===== Pass B: x = (tid>>5)<<9 | k<<5 | (tid&31); wires 4-6 (reg) =====
        const int baseB = ((tid >> 5) << 9) | (tid & 31);
        #pragma unroll
        for (int k = 0; k < 16; ++k) {
            ar[k] = sr[baseB | (k << 5)];
            ai[k] = si[baseB | (k << 5)];
        }
        REG_GATE(8, 4);   // wire 4 <-> x bit 8 <-> k bit 3
        REG_GATE(4, 5);
        REG_GATE(2, 6);

        if (l < N_LAYERS - 1) {
            // fused CNOT-ring permutation: scatter to y = sigma^{-1}(x)
            // y_j = XOR_{m>=j} x_m (j<=11); y_12 = (suffix parity at 0) ^ x_12
            #pragma unroll
            for (int k = 0; k < 16; ++k) {
                const int x = baseB | (k << 5);
                int t = x ^ (x >> 1); t ^= t >> 2; t ^= t >> 4; t ^= t >> 8;
                const int y = (t & 0x0FFF) | (((t ^ (x >> 12)) & 1) << 12);
                sr[y] = ar[k];
                si[y] = ai[k];
            }
            __syncthreads();
        }
    }

    // ---- fused readout: signs from final (permuted) index y ----
    float acc[N_OUT];
    #pragma unroll
    for (int o = 0; o < N_OUT; ++o) acc[o] = 0.f;

    {
        const int baseB = ((tid >> 5) << 9) | (tid & 31);
        #pragma unroll
        for (int k = 0; k < 16; ++k) {
            const int x = baseB | (k << 5);
            int t = x ^ (x >> 1); t ^= t >> 2; t ^= t >> 4; t ^= t >> 8;
            const int y = (t & 0x0FFF) | (((t ^ (x >> 12)) & 1) << 12);
            const float p = ar[k] * ar[k] + ai[k] * ai[k];
            #pragma unroll
            for (int o = 0; o < N_OUT; ++o)
                acc[o] += ((y >> (12 - o)) & 1) ? -p : p;
        }
    }

    #pragma unroll
    for (int off = 32; off >= 1; off >>= 1) {
        #pragma unroll
        for (int o = 0; o < N_OUT; ++o) acc[o] += __shfl_down(acc[o], off);
    }
    const int wave = tid >> 6;
    const int lane = tid & 63;
    if (lane == 0) {
        #pragma unroll
        for (int o = 0; o < N_OUT; ++o) red[wave][o] = acc[o];
    }
    __syncthreads();
    if (tid < N_OUT) {
        float s = 0.f;
        #pragma unroll
        for (int w = 0; w < NTHREADS / 64; ++w) s += red[w][tid];
        out[b * N_OUT + tid] = s;
    }
}

extern "C" void kernel_launch(void* const* d_in, const int* in_sizes, int n_in,
                              void* d_out, int out_size, void* d_ws, size_t ws_size,
                              hipStream_t stream) {
    const float* inputs  = (const float*)d_in[0];
    const float* weights = (const float*)d_in[1];
    const float* embed   = (const float*)d_in[2];
    float* out = (float*)d_out;
    vqc_kernel<<<BATCH, NTHREADS, 0, stream>>>(inputs, weights, embed, out);
}